// Round 9
// baseline (262.043 us; speedup 1.0000x reference)
//
#include <hip/hip_runtime.h>
#include <hip/hip_bf16.h>
#include <math.h>

typedef __attribute__((ext_vector_type(4))) float f32x4;
typedef __attribute__((ext_vector_type(8))) __bf16 bf16x8;
typedef __attribute__((ext_vector_type(8))) unsigned short u16x8;

__device__ __forceinline__ unsigned short f2bfu(float f) {
    unsigned u = __builtin_bit_cast(unsigned, f);
    u += 0x7fffu + ((u >> 16) & 1u);   // RNE
    return (unsigned short)(u >> 16);
}

__device__ __forceinline__ bf16x8 to_bf8(f32x4 x, f32x4 y) {
    bf16x8 o;
#pragma unroll
    for (int j = 0; j < 4; ++j) { o[j] = (__bf16)x[j]; o[j + 4] = (__bf16)y[j]; }
    return o;
}

__device__ __forceinline__ void gload_lds16(const void* g, void* l) {
    __builtin_amdgcn_global_load_lds(
        (__attribute__((address_space(1))) const void*)g,
        (__attribute__((address_space(3))) void*)l, 16, 0, 0);
}

template <int N>
__device__ __forceinline__ void waitcnt_vm() {
    if constexpr (N == 6)      asm volatile("s_waitcnt vmcnt(6)" ::: "memory");
    else if constexpr (N == 5) asm volatile("s_waitcnt vmcnt(5)" ::: "memory");
    else                       asm volatile("s_waitcnt vmcnt(0)" ::: "memory");
}

// ---------------------------------------------------------------- convs ----
struct ConvArgs {
    const float* w[6];
    const float* b[6];
};

__global__ __launch_bounds__(256) void conv_all(const float* __restrict__ X,
                                                ConvArgs args,
                                                float* __restrict__ out) {
    __shared__ float Xsp[30][208];   // [ci][6 zero-pad + 200 + 2 spare]
    __shared__ float Wg[30][212];    // [c][ci*7+kk]
    const int b = blockIdx.x, j = blockIdx.y;
    const int tid = threadIdx.x;
    const float* xb = X + (size_t)b * 6000;
    for (int i = tid; i < 30 * 208; i += 256) {
        const int ci = i / 208, p = i - ci * 208;
        float v = 0.f;
        if (p >= 6 && p < 206) v = xb[ci * 200 + (p - 6)];
        Xsp[ci][p] = v;
    }
    const float* wsrc = args.w[j];
    for (int i = tid; i < 6300; i += 256) Wg[i / 210][i % 210] = wsrc[i];
    __syncthreads();
    if (tid < 240) {
        const int c = tid >> 3;        // 0..29
        const int strip = tid & 7;     // 0..7
        const int l0 = strip * 25;
        float acc[25];
        const float bias = args.b[j][c];
#pragma unroll
        for (int o = 0; o < 25; ++o) acc[o] = bias;
        for (int ci = 0; ci < 30; ++ci) {
            float wv[7];
#pragma unroll
            for (int kk = 0; kk < 7; ++kk) wv[kk] = Wg[c][ci * 7 + kk];
            float xw[31];
#pragma unroll
            for (int i = 0; i < 31; ++i) xw[i] = Xsp[ci][l0 + i];
#pragma unroll
            for (int o = 0; o < 25; ++o) {
                float a = acc[o];
#pragma unroll
                for (int kk = 0; kk < 7; ++kk) a += xw[o + kk] * wv[kk];
                acc[o] = a;
            }
        }
        float* op = out + ((size_t)j * 64 + b) * 6000 + c * 200 + l0;
#pragma unroll
        for (int o = 0; o < 25; ++o) op[o] = acc[o];
    }
}

// ------------------------------------------------------------ attention ----
__global__ __launch_bounds__(256) void attn_k(const float* __restrict__ conv,
                                              const float* __restrict__ X,
                                              float* __restrict__ A_lin) {
    __shared__ float x1s[30][204], x2s[30][204], x3s[30][204];
    __shared__ float S[5][30][30];
    const int b = blockIdx.x, blk = blockIdx.y;
    const int tid = threadIdx.x;
    const f32x4* c1 = (const f32x4*)(conv + (((size_t)blk * 3 + 0) * 64 + b) * 6000);
    const f32x4* c2 = (const f32x4*)(conv + (((size_t)blk * 3 + 1) * 64 + b) * 6000);
    const f32x4* c3 = (const f32x4*)(conv + (((size_t)blk * 3 + 2) * 64 + b) * 6000);
    for (int i = tid; i < 1500; i += 256) {
        const int c = i / 50, q = i - c * 50;
        *(f32x4*)&x1s[c][q * 4] = c1[i];
        *(f32x4*)&x2s[c][q * 4] = c2[i];
        *(f32x4*)&x3s[c][q * 4] = c3[i];
    }
    __syncthreads();
    const float scale = 7.0710678118654752e-2f;  // 1/sqrt(200)
    if (blk == 0) {
        for (int idx = tid; idx < 900; idx += 256) {
            const int c = idx / 30, d = idx - c * 30;
            f32x4 a4 = {};
            for (int q = 0; q < 50; ++q) {
                const f32x4 x = *(const f32x4*)&x1s[c][q * 4];
                const f32x4 y = *(const f32x4*)&x2s[d][q * 4];
                a4 += x * y;
            }
            S[0][c][d] = (a4[0] + a4[1] + a4[2] + a4[3]) * scale;
        }
    } else {
        for (int idx = tid; idx < 4500; idx += 256) {
            const int h = idx / 900, rem = idx - h * 900;
            const int c = rem / 30, d = rem - c * 30;
            f32x4 a4 = {};
            for (int q = 0; q < 10; ++q) {
                const f32x4 x = *(const f32x4*)&x1s[c][h * 40 + q * 4];
                const f32x4 y = *(const f32x4*)&x2s[d][h * 40 + q * 4];
                a4 += x * y;
            }
            S[h][c][d] = (a4[0] + a4[1] + a4[2] + a4[3]) * scale;
        }
    }
    __syncthreads();
    const float* Xb = X + (size_t)b * 6000;
    float* Ab = A_lin + ((size_t)blk * 64 + b) * 6000;
    for (int u = tid; u < 1500; u += 256) {
        const int c = u / 50, q = u - c * 50;
        const int hh = (blk == 0) ? 0 : (q / 10);
        f32x4 a4 = {};
        for (int d = 0; d < 30; ++d) {
            const float sv = S[hh][c][d];
            const f32x4 v = *(const f32x4*)&x3s[d][q * 4];
            a4 += sv * v;
        }
        const f32x4 xv = *(const f32x4*)(Xb + c * 200 + q * 4);
        f32x4 o;
#pragma unroll
        for (int jj = 0; jj < 4; ++jj)
            o[jj] = 1.f / (1.f + __expf(-a4[jj])) + xv[jj];
        *(f32x4*)(Ab + c * 200 + q * 4) = o;
    }
}

// ------------------------------------------------------------------- BN ----
template <bool ADD>
__global__ __launch_bounds__(256) void bn_stats(const float* __restrict__ A,
                                                const float* __restrict__ O,
                                                float* __restrict__ part) {
    const int c = blockIdx.x, h = blockIdx.y, bs = blockIdx.z;
    const int tid = threadIdx.x;
    float s = 0.f, ss = 0.f;
    for (int i = tid; i < 1600; i += 256) {
        const int b = bs * 8 + i / 200, l = i % 200;
        const size_t idx = ((size_t)h * 64 + b) * 6000 + c * 200 + l;
        float v = A[idx];
        if constexpr (ADD) v += O[idx];
        s += v; ss += v * v;
    }
    for (int off = 32; off > 0; off >>= 1) { s += __shfl_down(s, off); ss += __shfl_down(ss, off); }
    __shared__ float rs[4], rss[4];
    const int wave = tid >> 6, lane = tid & 63;
    if (lane == 0) { rs[wave] = s; rss[wave] = ss; }
    __syncthreads();
    if (tid == 0) {
        float* p = part + (((size_t)h * 30 + c) * 8 + bs) * 2;
        p[0] = rs[0] + rs[1] + rs[2] + rs[3];
        p[1] = rss[0] + rss[1] + rss[2] + rss[3];
    }
}

__global__ __launch_bounds__(256) void bn_apply1(float* __restrict__ A,
                                                 unsigned short* __restrict__ Ab,
                                                 const float* __restrict__ part,
                                                 const float* __restrict__ g11,
                                                 const float* __restrict__ b11,
                                                 const float* __restrict__ g21,
                                                 const float* __restrict__ b21) {
    const int c = blockIdx.x, h = blockIdx.y, bs = blockIdx.z;
    const int tid = threadIdx.x;
    const float* p = part + (((size_t)h * 30 + c) * 8) * 2;
    float S = 0.f, SS = 0.f;
#pragma unroll
    for (int k = 0; k < 8; ++k) { S += p[k * 2]; SS += p[k * 2 + 1]; }
    const float mean = S * (1.f / 12800.f);
    const float var = SS * (1.f / 12800.f) - mean * mean;
    const float* gp = h ? g21 : g11;
    const float* bp = h ? b21 : b11;
    const float scale = gp[c] * rsqrtf(var + 1e-5f);
    const float shift = bp[c] - mean * scale;
    for (int i = tid; i < 1600; i += 256) {
        const int b = bs * 8 + i / 200, l = i % 200;
        const size_t idx = ((size_t)h * 64 + b) * 6000 + c * 200 + l;
        const float o = A[idx] * scale + shift;
        A[idx] = o;
        Ab[((size_t)h * 64 + b) * 6016 + c * 200 + l] = f2bfu(o);
    }
    if (c == 0) {   // zero K-pad cols 6000..6015 for this slice's 8 rows
        for (int i = tid; i < 8 * 16; i += 256) {
            const int b = bs * 8 + (i >> 4);
            Ab[((size_t)h * 64 + b) * 6016 + 6000 + (i & 15)] = 0;
        }
    }
}

__global__ __launch_bounds__(256) void bn_apply2(const float* __restrict__ A,
                                                 const float* __restrict__ O,
                                                 unsigned short* __restrict__ Cat,
                                                 const float* __restrict__ part,
                                                 const float* __restrict__ g12,
                                                 const float* __restrict__ b12,
                                                 const float* __restrict__ g22,
                                                 const float* __restrict__ b22) {
    const int c = blockIdx.x, h = blockIdx.y, bs = blockIdx.z;
    const int tid = threadIdx.x;
    const float* p = part + (((size_t)h * 30 + c) * 8) * 2;
    float S = 0.f, SS = 0.f;
#pragma unroll
    for (int k = 0; k < 8; ++k) { S += p[k * 2]; SS += p[k * 2 + 1]; }
    const float mean = S * (1.f / 12800.f);
    const float var = SS * (1.f / 12800.f) - mean * mean;
    const float* gp = h ? g22 : g12;
    const float* bp = h ? b22 : b12;
    const float scale = gp[c] * rsqrtf(var + 1e-5f);
    const float shift = bp[c] - mean * scale;
    for (int i = tid; i < 1600; i += 256) {
        const int b = bs * 8 + i / 200, l = i % 200;
        const size_t idx = ((size_t)h * 64 + b) * 6000 + c * 200 + l;
        const float o = (A[idx] + O[idx]) * scale + shift;
        Cat[(size_t)b * 12000 + (size_t)h * 6000 + c * 200 + l] = f2bfu(o);
    }
}

// ---------------- BN=128 depth-2 counted-vmcnt pipelined split-K GEMM ----
// Hoisted staging addresses: per-chunk base pointers precomputed once; the
// per-iter issue path is compare+select+add only (no 64-bit muls between
// barrier and load issue).
template <int MT>   // M = MT*16
__global__ __launch_bounds__(256) void gemm_pipe(const unsigned short* __restrict__ A,
                                                 const float* __restrict__ W,
                                                 unsigned short* __restrict__ P,
                                                 int N, int K, int KA,
                                                 int iters_total, int iters_per) {
    constexpr int M = MT * 16;
    constexpr int WB = 128 * 32 * 4;      // 16384 B (128 rows x 128 B)
    constexpr int AB = M * 32 * 2;        // M*64 B
    constexpr int ACH = AB / 1024;        // A chunks (= MT)
    constexpr int BUFSZ = WB + AB;
    constexpr int VMPS = 4 + ACH / 4;     // gload_lds per wave per stage (6 or 5)
    __shared__ __align__(16) char lds[2][BUFSZ];

    const int tid = threadIdx.x;
    const int wave = tid >> 6;
    const int lane = tid & 63;
    const int r = lane & 15;
    const int g = lane >> 4;
    const int n0 = blockIdx.x * 128;
    const int s = blockIdx.y;
    const int it0 = s * iters_per;
    int it1 = it0 + iters_per;
    if (it1 > iters_total) it1 = iters_total;
    const int nst = it1 - it0;

    f32x4 acc[MT][2] = {};

    // ---- hoisted staging addresses (indexed only by unrolled u) ----
    const float* wbase[4];
    const float* wclamp[4];
    int kth[4];
#pragma unroll
    for (int u = 0; u < 4; ++u) {
        const int c = wave + 4 * u;
        const int slot = c * 64 + lane;
        const int row = slot >> 3, jj = slot & 7;
        const int j = jj ^ (row & 7);
        int rn = n0 + row;
        if (rn > N - 1) rn = N - 1;
        wbase[u] = W + (size_t)rn * K + j * 4;
        wclamp[u] = W + (size_t)rn * K + (K - 4);
        kth[u] = K - 4 - j * 4;
    }
    const unsigned short* abase[ACH / 4];
#pragma unroll
    for (int u = 0; u < ACH / 4; ++u) {
        const int c = wave + 4 * u;
        const int slot = c * 64 + lane;
        const int m = slot >> 2, jj = slot & 3;
        const int j = jj ^ ((m >> 1) & 3);
        abase[u] = A + (size_t)m * KA + j * 8;
    }

    auto stage = [&](char* base, int it) {
        const int k0 = it * 32;
#pragma unroll
        for (int u = 0; u < 4; ++u) {           // W: 4 chunks/wave (16 total)
            const float* src = (k0 <= kth[u]) ? (wbase[u] + k0) : wclamp[u];
            gload_lds16(src, base + (wave + 4 * u) * 1024);
        }
        char* ab = base + WB;
#pragma unroll
        for (int u = 0; u < ACH / 4; ++u) {     // A: ACH/4 chunks/wave
            gload_lds16(abase[u] + k0, ab + (wave + 4 * u) * 1024);
        }
    };

    auto compute = [&](const char* base) {
        const float* Wb = (const float*)base;
        const unsigned short* Ab = (const unsigned short*)(base + WB);
        bf16x8 bfrag[2];
#pragma unroll
        for (int nt = 0; nt < 2; ++nt) {
            const int wr = (wave + 4 * nt) * 16 + r;
            const f32x4* Wrow = (const f32x4*)(Wb + wr * 32);
            bfrag[nt] = to_bf8(Wrow[(2 * g) ^ (r & 7)], Wrow[(2 * g + 1) ^ (r & 7)]);
        }
#pragma unroll
        for (int mt = 0; mt < MT; ++mt) {
            const int m = mt * 16 + r;
            const bf16x8 afrag = __builtin_bit_cast(
                bf16x8, ((const u16x8*)(Ab + (size_t)m * 32))[g ^ ((m >> 1) & 3)]);
            acc[mt][0] = __builtin_amdgcn_mfma_f32_16x16x32_bf16(afrag, bfrag[0], acc[mt][0], 0, 0, 0);
            acc[mt][1] = __builtin_amdgcn_mfma_f32_16x16x32_bf16(afrag, bfrag[1], acc[mt][1], 0, 0, 0);
        }
    };

    if (nst > 0) {
        stage(&lds[0][0], it0);
        if (nst > 1) {
            stage(&lds[1][0], it0 + 1);
            waitcnt_vm<VMPS>();
        } else {
            waitcnt_vm<0>();
        }
        __builtin_amdgcn_s_barrier();
        __builtin_amdgcn_sched_barrier(0);

        int cur = 0;
        for (int it = it0; it < it1; ++it) {
            compute(&lds[cur][0]);
            __builtin_amdgcn_sched_barrier(0);
            __builtin_amdgcn_s_barrier();          // buf[cur] free
            if (it + 2 < it1) stage(&lds[cur][0], it + 2);
            if (it + 1 < it1) {
                if (it + 2 < it1) waitcnt_vm<VMPS>();   // next buf ready, newest in flight
                else              waitcnt_vm<0>();
                __builtin_amdgcn_s_barrier();
                __builtin_amdgcn_sched_barrier(0);
            }
            cur ^= 1;
        }
    }

    unsigned short* Pp = P + (size_t)s * M * N;
#pragma unroll
    for (int nt = 0; nt < 2; ++nt) {
        const int col = n0 + (wave + 4 * nt) * 16 + r;
        if (col < N) {
#pragma unroll
            for (int mt = 0; mt < MT; ++mt) {
#pragma unroll
                for (int rr = 0; rr < 4; ++rr) {
                    const int row = mt * 16 + g * 4 + rr;
                    Pp[(size_t)row * N + col] = f2bfu(acc[mt][nt][rr]);
                }
            }
        }
    }
}

// Sum KS bf16 partials + bias -> fp32 (flat) or bf16 (stride KOUT, pad-zeroed).
template <bool OUT_BF16>
__global__ __launch_bounds__(256) void reduce_bias(const unsigned short* __restrict__ P,
                                                   const float* __restrict__ bias,
                                                   int KS, int MN, int N, int KOUT,
                                                   float* __restrict__ of,
                                                   unsigned short* __restrict__ ob) {
    const int gid0 = blockIdx.x * 256 + threadIdx.x;
    const int gstr = gridDim.x * 256;
    for (int idx = gid0; idx < MN; idx += gstr) {
        float v = bias[idx % N];
        for (int s = 0; s < KS; ++s) {
            const unsigned u = P[(size_t)s * MN + idx];
            v += __builtin_bit_cast(float, u << 16);
        }
        if constexpr (OUT_BF16) ob[(size_t)(idx / N) * KOUT + (idx % N)] = f2bfu(v);
        else of[idx] = v;
    }
    if constexpr (OUT_BF16) {
        if (KOUT > N) {
            const int M = MN / N, PADW = KOUT - N;
            for (int i = gid0; i < M * PADW; i += gstr)
                ob[(size_t)(i / PADW) * KOUT + N + (i % PADW)] = 0;
        }
    }
}

// ---------------------------------------------------------------- launch ----
extern "C" void kernel_launch(void* const* d_in, const int* in_sizes, int n_in,
                              void* d_out, int out_size, void* d_ws, size_t ws_size,
                              hipStream_t stream) {
    (void)in_sizes; (void)n_in; (void)out_size;
    const float* X = (const float*)d_in[0];
    ConvArgs ca;
    for (int j = 0; j < 6; ++j) {
        ca.w[j] = (const float*)d_in[1 + 2 * j];
        ca.b[j] = (const float*)d_in[2 + 2 * j];
    }
    const float* bn11_g = (const float*)d_in[13];
    const float* bn11_b = (const float*)d_in[14];
    const float* bn12_g = (const float*)d_in[15];
    const float* bn12_b = (const float*)d_in[16];
    const float* bn21_g = (const float*)d_in[17];
    const float* bn21_b = (const float*)d_in[18];
    const float* bn22_g = (const float*)d_in[19];
    const float* bn22_b = (const float*)d_in[20];
    const float* lin1_w = (const float*)d_in[21];
    const float* lin1_b = (const float*)d_in[22];
    const float* lin2_w = (const float*)d_in[23];
    const float* lin2_b = (const float*)d_in[24];
    const float* cw = (const float*)d_in[25];
    const float* cb = (const float*)d_in[26];
    float* out = (float*)d_out;

    // workspace layout (bytes):
    //   A_lin f32 [128][6000]        @ 0           (3,072,000)
    //   A_bf  bf16 [128][6016]       @ 3,072,000   (1,540,096)
    //   U region                     @ 4,612,096   (9,216,000):
    //     phase A: convout [6][64][6000] f32
    //     phase B: T_bf bf16[128][6016] @U, O f32[128][6000] @U+1,540,096,
    //              Cat bf16[64][12000] @U+4,612,096
    //   BNS bn partials              @ 13,828,096  (4,096)
    //   P partials                   @ 13,832,192  (rest, adaptive KS)
    char* w = (char*)d_ws;
    float* A_lin = (float*)w;
    unsigned short* A_bf = (unsigned short*)(w + 3072000);
    char* U = w + 4612096;
    float* convout = (float*)U;
    unsigned short* T_bf = (unsigned short*)U;
    float* O = (float*)(U + 1540096);
    unsigned short* Cat = (unsigned short*)(U + 4612096);
    float* BNS = (float*)(w + 13828096);
    unsigned short* P = (unsigned short*)(w + 13832192);

    const size_t avail = ws_size > 13832192 ? ws_size - 13832192 : 0;
    int KS12 = (int)(avail / 1536000);  // per-chunk bf16 partials: 128*6000*2 B
    if (KS12 > 16) KS12 = 16;           // 47*16 = 752 blocks = 2.94/CU vs 3/CU cap
    if (KS12 < 1) KS12 = 1;
    int KS3 = (int)(avail / 768000);    // per-chunk bf16 partials: 64*6000*2 B
    if (KS3 > 20) KS3 = 20;             // 47*20 = 940 blocks = 3.67/CU vs 4/CU cap
    if (KS3 < 1) KS3 = 1;

    conv_all<<<dim3(64, 6), 256, 0, stream>>>(X, ca, convout);
    attn_k<<<dim3(64, 2), 256, 0, stream>>>(convout, X, A_lin);
    bn_stats<false><<<dim3(30, 2, 8), 256, 0, stream>>>(A_lin, nullptr, BNS);
    bn_apply1<<<dim3(30, 2, 8), 256, 0, stream>>>(A_lin, A_bf, BNS, bn11_g, bn11_b, bn21_g, bn21_b);

    {
        const int it_tot = 188;  // 6016/32 (A zero-padded past 6000)
        const int it_per = (it_tot + KS12 - 1) / KS12;
        gemm_pipe<8><<<dim3(47, KS12), 256, 0, stream>>>(A_bf, lin1_w, P, 6000, 6000, 6016, it_tot, it_per);
        reduce_bias<true><<<dim3(768), 256, 0, stream>>>(P, lin1_b, KS12, 768000, 6000, 6016, nullptr, T_bf);
        gemm_pipe<8><<<dim3(47, KS12), 256, 0, stream>>>(T_bf, lin2_w, P, 6000, 6000, 6016, it_tot, it_per);
        reduce_bias<false><<<dim3(768), 256, 0, stream>>>(P, lin2_b, KS12, 768000, 6000, 6000, O, nullptr);
    }

    bn_stats<true><<<dim3(30, 2, 8), 256, 0, stream>>>(A_lin, O, BNS);
    bn_apply2<<<dim3(30, 2, 8), 256, 0, stream>>>(A_lin, O, Cat, BNS, bn12_g, bn12_b, bn22_g, bn22_b);

    {
        const int it_tot = 375;  // 12000/32, exact
        const int it_per = (it_tot + KS3 - 1) / KS3;
        gemm_pipe<4><<<dim3(47, KS3), 256, 0, stream>>>(Cat, cw, P, 6000, 12000, 12000, it_tot, it_per);
        reduce_bias<false><<<dim3(768), 256, 0, stream>>>(P, cb, KS3, 384000, 6000, 6000, out, nullptr);
    }
}

// Round 10
// 257.924 us; speedup vs baseline: 1.0160x; 1.0160x over previous
//
#include <hip/hip_runtime.h>
#include <hip/hip_bf16.h>
#include <math.h>

typedef __attribute__((ext_vector_type(4))) float f32x4;
typedef __attribute__((ext_vector_type(8))) __bf16 bf16x8;
typedef __attribute__((ext_vector_type(8))) unsigned short u16x8;

__device__ __forceinline__ unsigned short f2bfu(float f) {
    unsigned u = __builtin_bit_cast(unsigned, f);
    u += 0x7fffu + ((u >> 16) & 1u);   // RNE
    return (unsigned short)(u >> 16);
}

__device__ __forceinline__ bf16x8 to_bf8(f32x4 x, f32x4 y) {
    bf16x8 o;
#pragma unroll
    for (int j = 0; j < 4; ++j) { o[j] = (__bf16)x[j]; o[j + 4] = (__bf16)y[j]; }
    return o;
}

__device__ __forceinline__ void gload_lds16(const void* g, void* l) {
    __builtin_amdgcn_global_load_lds(
        (__attribute__((address_space(1))) const void*)g,
        (__attribute__((address_space(3))) void*)l, 16, 0, 0);
}

// keep `newer` stages (VMPS gload_lds each) in flight; oldest ones complete
template <int VMPS>
__device__ __forceinline__ void wait_newer(int newer) {
    if (newer >= 2) {
        if constexpr (VMPS == 6) asm volatile("s_waitcnt vmcnt(12)" ::: "memory");
        else                     asm volatile("s_waitcnt vmcnt(10)" ::: "memory");
    } else if (newer == 1) {
        if constexpr (VMPS == 6) asm volatile("s_waitcnt vmcnt(6)" ::: "memory");
        else                     asm volatile("s_waitcnt vmcnt(5)" ::: "memory");
    } else {
        asm volatile("s_waitcnt vmcnt(0)" ::: "memory");
    }
}

// ---------------------------------------------------------------- convs ----
struct ConvArgs {
    const float* w[6];
    const float* b[6];
};

__global__ __launch_bounds__(256) void conv_all(const float* __restrict__ X,
                                                ConvArgs args,
                                                float* __restrict__ out) {
    __shared__ float Xsp[30][208];   // [ci][6 zero-pad + 200 + 2 spare]
    __shared__ float Wg[30][212];    // [c][ci*7+kk]
    const int b = blockIdx.x, j = blockIdx.y;
    const int tid = threadIdx.x;
    const float* xb = X + (size_t)b * 6000;
    for (int i = tid; i < 30 * 208; i += 256) {
        const int ci = i / 208, p = i - ci * 208;
        float v = 0.f;
        if (p >= 6 && p < 206) v = xb[ci * 200 + (p - 6)];
        Xsp[ci][p] = v;
    }
    const float* wsrc = args.w[j];
    for (int i = tid; i < 6300; i += 256) Wg[i / 210][i % 210] = wsrc[i];
    __syncthreads();
    if (tid < 240) {
        const int c = tid >> 3;        // 0..29
        const int strip = tid & 7;     // 0..7
        const int l0 = strip * 25;
        float acc[25];
        const float bias = args.b[j][c];
#pragma unroll
        for (int o = 0; o < 25; ++o) acc[o] = bias;
        for (int ci = 0; ci < 30; ++ci) {
            float wv[7];
#pragma unroll
            for (int kk = 0; kk < 7; ++kk) wv[kk] = Wg[c][ci * 7 + kk];
            float xw[31];
#pragma unroll
            for (int i = 0; i < 31; ++i) xw[i] = Xsp[ci][l0 + i];
#pragma unroll
            for (int o = 0; o < 25; ++o) {
                float a = acc[o];
#pragma unroll
                for (int kk = 0; kk < 7; ++kk) a += xw[o + kk] * wv[kk];
                acc[o] = a;
            }
        }
        float* op = out + ((size_t)j * 64 + b) * 6000 + c * 200 + l0;
#pragma unroll
        for (int o = 0; o < 25; ++o) op[o] = acc[o];
    }
}

// ------------------------------------------------------------ attention ----
__global__ __launch_bounds__(256) void attn_k(const float* __restrict__ conv,
                                              const float* __restrict__ X,
                                              float* __restrict__ A_lin) {
    __shared__ float x1s[30][204], x2s[30][204], x3s[30][204];
    __shared__ float S[5][30][30];
    const int b = blockIdx.x, blk = blockIdx.y;
    const int tid = threadIdx.x;
    const f32x4* c1 = (const f32x4*)(conv + (((size_t)blk * 3 + 0) * 64 + b) * 6000);
    const f32x4* c2 = (const f32x4*)(conv + (((size_t)blk * 3 + 1) * 64 + b) * 6000);
    const f32x4* c3 = (const f32x4*)(conv + (((size_t)blk * 3 + 2) * 64 + b) * 6000);
    for (int i = tid; i < 1500; i += 256) {
        const int c = i / 50, q = i - c * 50;
        *(f32x4*)&x1s[c][q * 4] = c1[i];
        *(f32x4*)&x2s[c][q * 4] = c2[i];
        *(f32x4*)&x3s[c][q * 4] = c3[i];
    }
    __syncthreads();
    const float scale = 7.0710678118654752e-2f;  // 1/sqrt(200)
    if (blk == 0) {
        for (int idx = tid; idx < 900; idx += 256) {
            const int c = idx / 30, d = idx - c * 30;
            f32x4 a4 = {};
            for (int q = 0; q < 50; ++q) {
                const f32x4 x = *(const f32x4*)&x1s[c][q * 4];
                const f32x4 y = *(const f32x4*)&x2s[d][q * 4];
                a4 += x * y;
            }
            S[0][c][d] = (a4[0] + a4[1] + a4[2] + a4[3]) * scale;
        }
    } else {
        for (int idx = tid; idx < 4500; idx += 256) {
            const int h = idx / 900, rem = idx - h * 900;
            const int c = rem / 30, d = rem - c * 30;
            f32x4 a4 = {};
            for (int q = 0; q < 10; ++q) {
                const f32x4 x = *(const f32x4*)&x1s[c][h * 40 + q * 4];
                const f32x4 y = *(const f32x4*)&x2s[d][h * 40 + q * 4];
                a4 += x * y;
            }
            S[h][c][d] = (a4[0] + a4[1] + a4[2] + a4[3]) * scale;
        }
    }
    __syncthreads();
    const float* Xb = X + (size_t)b * 6000;
    float* Ab = A_lin + ((size_t)blk * 64 + b) * 6000;
    for (int u = tid; u < 1500; u += 256) {
        const int c = u / 50, q = u - c * 50;
        const int hh = (blk == 0) ? 0 : (q / 10);
        f32x4 a4 = {};
        for (int d = 0; d < 30; ++d) {
            const float sv = S[hh][c][d];
            const f32x4 v = *(const f32x4*)&x3s[d][q * 4];
            a4 += sv * v;
        }
        const f32x4 xv = *(const f32x4*)(Xb + c * 200 + q * 4);
        f32x4 o;
#pragma unroll
        for (int jj = 0; jj < 4; ++jj)
            o[jj] = 1.f / (1.f + __expf(-a4[jj])) + xv[jj];
        *(f32x4*)(Ab + c * 200 + q * 4) = o;
    }
}

// ------------------------------------------------------------------- BN ----
// Fused stats+apply: grid (30,2,8); every block redundantly computes its
// (c,h) channel's full stats (identical, deterministic), applies to its
// 8-batch slice. Saves a dispatch + stats round-trip vs two-phase.
__global__ __launch_bounds__(256) void bn_fused1(float* __restrict__ A,
                                                 unsigned short* __restrict__ Ab,
                                                 const float* __restrict__ g11,
                                                 const float* __restrict__ b11,
                                                 const float* __restrict__ g21,
                                                 const float* __restrict__ b21) {
    const int c = blockIdx.x, h = blockIdx.y, bs = blockIdx.z;
    const int tid = threadIdx.x;
    const size_t cbase = (size_t)h * 64 * 6000 + c * 200;
    float s = 0.f, ss = 0.f;
    for (int i = tid; i < 12800; i += 256) {
        const int b = i / 200, l = i - b * 200;
        const float v = A[cbase + (size_t)b * 6000 + l];
        s += v; ss += v * v;
    }
    for (int off = 32; off > 0; off >>= 1) { s += __shfl_down(s, off); ss += __shfl_down(ss, off); }
    __shared__ float rs[4], rss[4];
    __shared__ float sc_sh, sh_sh;
    const int wave = tid >> 6, lane = tid & 63;
    if (lane == 0) { rs[wave] = s; rss[wave] = ss; }
    __syncthreads();
    if (tid == 0) {
        const float S = rs[0] + rs[1] + rs[2] + rs[3];
        const float SS = rss[0] + rss[1] + rss[2] + rss[3];
        const float mean = S * (1.f / 12800.f);
        const float var = SS * (1.f / 12800.f) - mean * mean;
        const float* gp = h ? g21 : g11;
        const float* bp = h ? b21 : b11;
        const float scale = gp[c] * rsqrtf(var + 1e-5f);
        sc_sh = scale;
        sh_sh = bp[c] - mean * scale;
    }
    __syncthreads();
    const float scale = sc_sh, shift = sh_sh;
    for (int i = tid; i < 1600; i += 256) {
        const int b = bs * 8 + i / 200, l = i % 200;
        const size_t idx = ((size_t)h * 64 + b) * 6000 + c * 200 + l;
        const float o = A[idx] * scale + shift;
        A[idx] = o;
        Ab[((size_t)h * 64 + b) * 6016 + c * 200 + l] = f2bfu(o);
    }
    if (c == 0) {   // zero K-pad cols 6000..6015 for this slice's 8 rows
        for (int i = tid; i < 8 * 16; i += 256) {
            const int b = bs * 8 + (i >> 4);
            Ab[((size_t)h * 64 + b) * 6016 + 6000 + (i & 15)] = 0;
        }
    }
}

__global__ __launch_bounds__(256) void bn_fused2(const float* __restrict__ A,
                                                 const float* __restrict__ O,
                                                 unsigned short* __restrict__ Cat,
                                                 const float* __restrict__ g12,
                                                 const float* __restrict__ b12,
                                                 const float* __restrict__ g22,
                                                 const float* __restrict__ b22) {
    const int c = blockIdx.x, h = blockIdx.y, bs = blockIdx.z;
    const int tid = threadIdx.x;
    const size_t cbase = (size_t)h * 64 * 6000 + c * 200;
    float s = 0.f, ss = 0.f;
    for (int i = tid; i < 12800; i += 256) {
        const int b = i / 200, l = i - b * 200;
        const size_t idx = cbase + (size_t)b * 6000 + l;
        const float v = A[idx] + O[idx];
        s += v; ss += v * v;
    }
    for (int off = 32; off > 0; off >>= 1) { s += __shfl_down(s, off); ss += __shfl_down(ss, off); }
    __shared__ float rs[4], rss[4];
    __shared__ float sc_sh, sh_sh;
    const int wave = tid >> 6, lane = tid & 63;
    if (lane == 0) { rs[wave] = s; rss[wave] = ss; }
    __syncthreads();
    if (tid == 0) {
        const float S = rs[0] + rs[1] + rs[2] + rs[3];
        const float SS = rss[0] + rss[1] + rss[2] + rss[3];
        const float mean = S * (1.f / 12800.f);
        const float var = SS * (1.f / 12800.f) - mean * mean;
        const float* gp = h ? g22 : g12;
        const float* bp = h ? b22 : b12;
        const float scale = gp[c] * rsqrtf(var + 1e-5f);
        sc_sh = scale;
        sh_sh = bp[c] - mean * scale;
    }
    __syncthreads();
    const float scale = sc_sh, shift = sh_sh;
    for (int i = tid; i < 1600; i += 256) {
        const int b = bs * 8 + i / 200, l = i % 200;
        const size_t idx = ((size_t)h * 64 + b) * 6000 + c * 200 + l;
        const float o = (A[idx] + O[idx]) * scale + shift;
        Cat[(size_t)b * 12000 + (size_t)h * 6000 + c * 200 + l] = f2bfu(o);
    }
}

// ---------------- BN=128 depth-3 counted-vmcnt pipelined split-K GEMM ----
// 3 LDS buffers: stage(it+3) issued during iter it -> 2 iterations of slack
// against HBM latency; waits keep 2 stages (2*VMPS loads) in flight.
template <int MT>   // M = MT*16
__global__ __launch_bounds__(256) void gemm_pipe(const unsigned short* __restrict__ A,
                                                 const float* __restrict__ W,
                                                 unsigned short* __restrict__ P,
                                                 int N, int K, int KA,
                                                 int iters_total, int iters_per) {
    constexpr int M = MT * 16;
    constexpr int WB = 128 * 32 * 4;      // 16384 B (128 rows x 128 B)
    constexpr int AB = M * 32 * 2;        // M*64 B
    constexpr int ACH = AB / 1024;        // A chunks (= MT)
    constexpr int BUFSZ = WB + AB;
    constexpr int VMPS = 4 + ACH / 4;     // gload_lds per wave per stage (6 or 5)
    __shared__ __align__(16) char lds[3][BUFSZ];

    const int tid = threadIdx.x;
    const int wave = tid >> 6;
    const int lane = tid & 63;
    const int r = lane & 15;
    const int g = lane >> 4;
    const int n0 = blockIdx.x * 128;
    const int s = blockIdx.y;
    const int it0 = s * iters_per;
    int it1 = it0 + iters_per;
    if (it1 > iters_total) it1 = iters_total;
    const int nst = it1 - it0;

    f32x4 acc[MT][2] = {};

    // ---- hoisted staging addresses (indexed only by unrolled u) ----
    const float* wbase[4];
    const float* wclamp[4];
    int kth[4];
#pragma unroll
    for (int u = 0; u < 4; ++u) {
        const int c = wave + 4 * u;
        const int slot = c * 64 + lane;
        const int row = slot >> 3, jj = slot & 7;
        const int j = jj ^ (row & 7);
        int rn = n0 + row;
        if (rn > N - 1) rn = N - 1;
        wbase[u] = W + (size_t)rn * K + j * 4;
        wclamp[u] = W + (size_t)rn * K + (K - 4);
        kth[u] = K - 4 - j * 4;
    }
    const unsigned short* abase[ACH / 4];
#pragma unroll
    for (int u = 0; u < ACH / 4; ++u) {
        const int c = wave + 4 * u;
        const int slot = c * 64 + lane;
        const int m = slot >> 2, jj = slot & 3;
        const int j = jj ^ ((m >> 1) & 3);
        abase[u] = A + (size_t)m * KA + j * 8;
    }

    auto stage = [&](char* base, int it) {
        const int k0 = it * 32;
#pragma unroll
        for (int u = 0; u < 4; ++u) {           // W: 4 chunks/wave (16 total)
            const float* src = (k0 <= kth[u]) ? (wbase[u] + k0) : wclamp[u];
            gload_lds16(src, base + (wave + 4 * u) * 1024);
        }
        char* ab = base + WB;
#pragma unroll
        for (int u = 0; u < ACH / 4; ++u) {     // A: ACH/4 chunks/wave
            gload_lds16(abase[u] + k0, ab + (wave + 4 * u) * 1024);
        }
    };

    auto compute = [&](const char* base) {
        const float* Wb = (const float*)base;
        const unsigned short* Ab = (const unsigned short*)(base + WB);
        bf16x8 bfrag[2];
#pragma unroll
        for (int nt = 0; nt < 2; ++nt) {
            const int wr = (wave + 4 * nt) * 16 + r;
            const f32x4* Wrow = (const f32x4*)(Wb + wr * 32);
            bfrag[nt] = to_bf8(Wrow[(2 * g) ^ (r & 7)], Wrow[(2 * g + 1) ^ (r & 7)]);
        }
#pragma unroll
        for (int mt = 0; mt < MT; ++mt) {
            const int m = mt * 16 + r;
            const bf16x8 afrag = __builtin_bit_cast(
                bf16x8, ((const u16x8*)(Ab + (size_t)m * 32))[g ^ ((m >> 1) & 3)]);
            acc[mt][0] = __builtin_amdgcn_mfma_f32_16x16x32_bf16(afrag, bfrag[0], acc[mt][0], 0, 0, 0);
            acc[mt][1] = __builtin_amdgcn_mfma_f32_16x16x32_bf16(afrag, bfrag[1], acc[mt][1], 0, 0, 0);
        }
    };

    if (nst > 0) {
        const int p = nst < 3 ? nst : 3;
        stage(&lds[0][0], it0);
        if (p > 1) stage(&lds[1][0], it0 + 1);
        if (p > 2) stage(&lds[2][0], it0 + 2);
        wait_newer<VMPS>(p - 1);                 // oldest stage complete
        __builtin_amdgcn_s_barrier();
        __builtin_amdgcn_sched_barrier(0);

        int bi = 0;
        for (int it = it0; it < it1; ++it) {
            compute(&lds[bi][0]);
            __builtin_amdgcn_sched_barrier(0);
            __builtin_amdgcn_s_barrier();          // all waves done reading buf bi
            if (it + 3 < it1) stage(&lds[bi][0], it + 3);
            if (it + 1 < it1) {
                const int last = it1 - 1;
                const int newer = ((it + 3 < last ? it + 3 : last)) - (it + 1);
                wait_newer<VMPS>(newer);           // stage(it+1) complete
                __builtin_amdgcn_s_barrier();
                __builtin_amdgcn_sched_barrier(0);
            }
            bi = bi == 2 ? 0 : bi + 1;
        }
    }

    unsigned short* Pp = P + (size_t)s * M * N;
#pragma unroll
    for (int nt = 0; nt < 2; ++nt) {
        const int col = n0 + (wave + 4 * nt) * 16 + r;
        if (col < N) {
#pragma unroll
            for (int mt = 0; mt < MT; ++mt) {
#pragma unroll
                for (int rr = 0; rr < 4; ++rr) {
                    const int row = mt * 16 + g * 4 + rr;
                    Pp[(size_t)row * N + col] = f2bfu(acc[mt][nt][rr]);
                }
            }
        }
    }
}

// Sum KS bf16 partials + bias -> fp32 (flat) or bf16 (stride KOUT, pad-zeroed).
template <bool OUT_BF16>
__global__ __launch_bounds__(256) void reduce_bias(const unsigned short* __restrict__ P,
                                                   const float* __restrict__ bias,
                                                   int KS, int MN, int N, int KOUT,
                                                   float* __restrict__ of,
                                                   unsigned short* __restrict__ ob) {
    const int gid0 = blockIdx.x * 256 + threadIdx.x;
    const int gstr = gridDim.x * 256;
    for (int idx = gid0; idx < MN; idx += gstr) {
        float v = bias[idx % N];
        for (int s = 0; s < KS; ++s) {
            const unsigned u = P[(size_t)s * MN + idx];
            v += __builtin_bit_cast(float, u << 16);
        }
        if constexpr (OUT_BF16) ob[(size_t)(idx / N) * KOUT + (idx % N)] = f2bfu(v);
        else of[idx] = v;
    }
    if constexpr (OUT_BF16) {
        if (KOUT > N) {
            const int M = MN / N, PADW = KOUT - N;
            for (int i = gid0; i < M * PADW; i += gstr)
                ob[(size_t)(i / PADW) * KOUT + N + (i % PADW)] = 0;
        }
    }
}

// ---------------------------------------------------------------- launch ----
extern "C" void kernel_launch(void* const* d_in, const int* in_sizes, int n_in,
                              void* d_out, int out_size, void* d_ws, size_t ws_size,
                              hipStream_t stream) {
    (void)in_sizes; (void)n_in; (void)out_size;
    const float* X = (const float*)d_in[0];
    ConvArgs ca;
    for (int j = 0; j < 6; ++j) {
        ca.w[j] = (const float*)d_in[1 + 2 * j];
        ca.b[j] = (const float*)d_in[2 + 2 * j];
    }
    const float* bn11_g = (const float*)d_in[13];
    const float* bn11_b = (const float*)d_in[14];
    const float* bn12_g = (const float*)d_in[15];
    const float* bn12_b = (const float*)d_in[16];
    const float* bn21_g = (const float*)d_in[17];
    const float* bn21_b = (const float*)d_in[18];
    const float* bn22_g = (const float*)d_in[19];
    const float* bn22_b = (const float*)d_in[20];
    const float* lin1_w = (const float*)d_in[21];
    const float* lin1_b = (const float*)d_in[22];
    const float* lin2_w = (const float*)d_in[23];
    const float* lin2_b = (const float*)d_in[24];
    const float* cw = (const float*)d_in[25];
    const float* cb = (const float*)d_in[26];
    float* out = (float*)d_out;

    // workspace layout (bytes):
    //   A_lin f32 [128][6000]        @ 0           (3,072,000)
    //   A_bf  bf16 [128][6016]       @ 3,072,000   (1,540,096)
    //   U region                     @ 4,612,096   (9,216,000):
    //     phase A: convout [6][64][6000] f32
    //     phase B: T_bf bf16[128][6016] @U, O f32[128][6000] @U+1,540,096,
    //              Cat bf16[64][12000] @U+4,612,096
    //   P partials                   @ 13,832,192  (rest, adaptive KS)
    char* w = (char*)d_ws;
    float* A_lin = (float*)w;
    unsigned short* A_bf = (unsigned short*)(w + 3072000);
    char* U = w + 4612096;
    float* convout = (float*)U;
    unsigned short* T_bf = (unsigned short*)U;
    float* O = (float*)(U + 1540096);
    unsigned short* Cat = (unsigned short*)(U + 4612096);
    unsigned short* P = (unsigned short*)(w + 13832192);

    const size_t avail = ws_size > 13832192 ? ws_size - 13832192 : 0;
    int KS12 = (int)(avail / 1536000);  // per-chunk bf16 partials: 128*6000*2 B
    if (KS12 > 10) KS12 = 10;           // 47*10 = 470 blocks, one round @ 2/CU (72KB LDS)
    if (KS12 < 1) KS12 = 1;
    int KS3 = (int)(avail / 768000);    // per-chunk bf16 partials: 64*6000*2 B
    if (KS3 > 10) KS3 = 10;             // 47*10 = 470 blocks, one round @ 2/CU (60KB LDS)
    if (KS3 < 1) KS3 = 1;

    conv_all<<<dim3(64, 6), 256, 0, stream>>>(X, ca, convout);
    attn_k<<<dim3(64, 2), 256, 0, stream>>>(convout, X, A_lin);
    bn_fused1<<<dim3(30, 2, 8), 256, 0, stream>>>(A_lin, A_bf, bn11_g, bn11_b, bn21_g, bn21_b);

    {
        const int it_tot = 188;  // 6016/32 (A zero-padded past 6000)
        const int it_per = (it_tot + KS12 - 1) / KS12;
        gemm_pipe<8><<<dim3(47, KS12), 256, 0, stream>>>(A_bf, lin1_w, P, 6000, 6000, 6016, it_tot, it_per);
        reduce_bias<true><<<dim3(768), 256, 0, stream>>>(P, lin1_b, KS12, 768000, 6000, 6016, nullptr, T_bf);
        gemm_pipe<8><<<dim3(47, KS12), 256, 0, stream>>>(T_bf, lin2_w, P, 6000, 6000, 6016, it_tot, it_per);
        reduce_bias<false><<<dim3(768), 256, 0, stream>>>(P, lin2_b, KS12, 768000, 6000, 6000, O, nullptr);
    }

    bn_fused2<<<dim3(30, 2, 8), 256, 0, stream>>>(A_lin, O, Cat, bn12_g, bn12_b, bn22_g, bn22_b);

    {
        const int it_tot = 375;  // 12000/32, exact
        const int it_per = (it_tot + KS3 - 1) / KS3;
        gemm_pipe<4><<<dim3(47, KS3), 256, 0, stream>>>(Cat, cw, P, 6000, 12000, 12000, it_tot, it_per);
        reduce_bias<false><<<dim3(768), 256, 0, stream>>>(P, cb, KS3, 384000, 6000, 6000, out, nullptr);
    }
}

// Round 11
// 239.965 us; speedup vs baseline: 1.0920x; 1.0748x over previous
//
#include <hip/hip_runtime.h>
#include <hip/hip_bf16.h>
#include <math.h>

typedef __attribute__((ext_vector_type(4))) float f32x4;
typedef __attribute__((ext_vector_type(8))) __bf16 bf16x8;
typedef __attribute__((ext_vector_type(8))) unsigned short u16x8;

__device__ __forceinline__ unsigned short f2bfu(float f) {
    unsigned u = __builtin_bit_cast(unsigned, f);
    u += 0x7fffu + ((u >> 16) & 1u);   // RNE
    return (unsigned short)(u >> 16);
}

__device__ __forceinline__ bf16x8 to_bf8(f32x4 x, f32x4 y) {
    bf16x8 o;
#pragma unroll
    for (int j = 0; j < 4; ++j) { o[j] = (__bf16)x[j]; o[j + 4] = (__bf16)y[j]; }
    return o;
}

__device__ __forceinline__ void gload_lds16(const void* g, void* l) {
    __builtin_amdgcn_global_load_lds(
        (__attribute__((address_space(1))) const void*)g,
        (__attribute__((address_space(3))) void*)l, 16, 0, 0);
}

template <int N>
__device__ __forceinline__ void waitcnt_vm() {
    if constexpr (N == 8)      asm volatile("s_waitcnt vmcnt(8)" ::: "memory");
    else if constexpr (N == 6) asm volatile("s_waitcnt vmcnt(6)" ::: "memory");
    else                       asm volatile("s_waitcnt vmcnt(0)" ::: "memory");
}

// ---------------------------------------------------------------- convs ----
struct ConvArgs {
    const float* w[6];
    const float* b[6];
};

__global__ __launch_bounds__(256) void conv_all(const float* __restrict__ X,
                                                ConvArgs args,
                                                float* __restrict__ out) {
    __shared__ float Xsp[30][208];   // [ci][6 zero-pad + 200 + 2 spare]
    __shared__ float Wg[30][212];    // [c][ci*7+kk]
    const int b = blockIdx.x, j = blockIdx.y;
    const int tid = threadIdx.x;
    const float* xb = X + (size_t)b * 6000;
    for (int i = tid; i < 30 * 208; i += 256) {
        const int ci = i / 208, p = i - ci * 208;
        float v = 0.f;
        if (p >= 6 && p < 206) v = xb[ci * 200 + (p - 6)];
        Xsp[ci][p] = v;
    }
    const float* wsrc = args.w[j];
    for (int i = tid; i < 6300; i += 256) Wg[i / 210][i % 210] = wsrc[i];
    __syncthreads();
    if (tid < 240) {
        const int c = tid >> 3;        // 0..29
        const int strip = tid & 7;     // 0..7
        const int l0 = strip * 25;
        float acc[25];
        const float bias = args.b[j][c];
#pragma unroll
        for (int o = 0; o < 25; ++o) acc[o] = bias;
        for (int ci = 0; ci < 30; ++ci) {
            float wv[7];
#pragma unroll
            for (int kk = 0; kk < 7; ++kk) wv[kk] = Wg[c][ci * 7 + kk];
            float xw[31];
#pragma unroll
            for (int i = 0; i < 31; ++i) xw[i] = Xsp[ci][l0 + i];
#pragma unroll
            for (int o = 0; o < 25; ++o) {
                float a = acc[o];
#pragma unroll
                for (int kk = 0; kk < 7; ++kk) a += xw[o + kk] * wv[kk];
                acc[o] = a;
            }
        }
        float* op = out + ((size_t)j * 64 + b) * 6000 + c * 200 + l0;
#pragma unroll
        for (int o = 0; o < 25; ++o) op[o] = acc[o];
    }
}

// ------------------------------------------------------------ attention ----
__global__ __launch_bounds__(256) void attn_k(const float* __restrict__ conv,
                                              const float* __restrict__ X,
                                              float* __restrict__ A_lin) {
    __shared__ float x1s[30][204], x2s[30][204], x3s[30][204];
    __shared__ float S[5][30][30];
    const int b = blockIdx.x, blk = blockIdx.y;
    const int tid = threadIdx.x;
    const f32x4* c1 = (const f32x4*)(conv + (((size_t)blk * 3 + 0) * 64 + b) * 6000);
    const f32x4* c2 = (const f32x4*)(conv + (((size_t)blk * 3 + 1) * 64 + b) * 6000);
    const f32x4* c3 = (const f32x4*)(conv + (((size_t)blk * 3 + 2) * 64 + b) * 6000);
    for (int i = tid; i < 1500; i += 256) {
        const int c = i / 50, q = i - c * 50;
        *(f32x4*)&x1s[c][q * 4] = c1[i];
        *(f32x4*)&x2s[c][q * 4] = c2[i];
        *(f32x4*)&x3s[c][q * 4] = c3[i];
    }
    __syncthreads();
    const float scale = 7.0710678118654752e-2f;  // 1/sqrt(200)
    if (blk == 0) {
        for (int idx = tid; idx < 900; idx += 256) {
            const int c = idx / 30, d = idx - c * 30;
            f32x4 a4 = {};
            for (int q = 0; q < 50; ++q) {
                const f32x4 x = *(const f32x4*)&x1s[c][q * 4];
                const f32x4 y = *(const f32x4*)&x2s[d][q * 4];
                a4 += x * y;
            }
            S[0][c][d] = (a4[0] + a4[1] + a4[2] + a4[3]) * scale;
        }
    } else {
        for (int idx = tid; idx < 4500; idx += 256) {
            const int h = idx / 900, rem = idx - h * 900;
            const int c = rem / 30, d = rem - c * 30;
            f32x4 a4 = {};
            for (int q = 0; q < 10; ++q) {
                const f32x4 x = *(const f32x4*)&x1s[c][h * 40 + q * 4];
                const f32x4 y = *(const f32x4*)&x2s[d][h * 40 + q * 4];
                a4 += x * y;
            }
            S[h][c][d] = (a4[0] + a4[1] + a4[2] + a4[3]) * scale;
        }
    }
    __syncthreads();
    const float* Xb = X + (size_t)b * 6000;
    float* Ab = A_lin + ((size_t)blk * 64 + b) * 6000;
    for (int u = tid; u < 1500; u += 256) {
        const int c = u / 50, q = u - c * 50;
        const int hh = (blk == 0) ? 0 : (q / 10);
        f32x4 a4 = {};
        for (int d = 0; d < 30; ++d) {
            const float sv = S[hh][c][d];
            const f32x4 v = *(const f32x4*)&x3s[d][q * 4];
            a4 += sv * v;
        }
        const f32x4 xv = *(const f32x4*)(Xb + c * 200 + q * 4);
        f32x4 o;
#pragma unroll
        for (int jj = 0; jj < 4; ++jj)
            o[jj] = 1.f / (1.f + __expf(-a4[jj])) + xv[jj];
        *(f32x4*)(Ab + c * 200 + q * 4) = o;
    }
}

// ------------------------------------------------------------------- BN ----
__global__ __launch_bounds__(256) void bn_fused1(float* __restrict__ A,
                                                 unsigned short* __restrict__ Ab,
                                                 const float* __restrict__ g11,
                                                 const float* __restrict__ b11,
                                                 const float* __restrict__ g21,
                                                 const float* __restrict__ b21) {
    const int c = blockIdx.x, h = blockIdx.y, bs = blockIdx.z;
    const int tid = threadIdx.x;
    const size_t cbase = (size_t)h * 64 * 6000 + c * 200;
    float s = 0.f, ss = 0.f;
    for (int i = tid; i < 12800; i += 256) {
        const int b = i / 200, l = i - b * 200;
        const float v = A[cbase + (size_t)b * 6000 + l];
        s += v; ss += v * v;
    }
    for (int off = 32; off > 0; off >>= 1) { s += __shfl_down(s, off); ss += __shfl_down(ss, off); }
    __shared__ float rs[4], rss[4];
    __shared__ float sc_sh, sh_sh;
    const int wave = tid >> 6, lane = tid & 63;
    if (lane == 0) { rs[wave] = s; rss[wave] = ss; }
    __syncthreads();
    if (tid == 0) {
        const float S = rs[0] + rs[1] + rs[2] + rs[3];
        const float SS = rss[0] + rss[1] + rss[2] + rss[3];
        const float mean = S * (1.f / 12800.f);
        const float var = SS * (1.f / 12800.f) - mean * mean;
        const float* gp = h ? g21 : g11;
        const float* bp = h ? b21 : b11;
        const float scale = gp[c] * rsqrtf(var + 1e-5f);
        sc_sh = scale;
        sh_sh = bp[c] - mean * scale;
    }
    __syncthreads();
    const float scale = sc_sh, shift = sh_sh;
    for (int i = tid; i < 1600; i += 256) {
        const int b = bs * 8 + i / 200, l = i % 200;
        const size_t idx = ((size_t)h * 64 + b) * 6000 + c * 200 + l;
        const float o = A[idx] * scale + shift;
        A[idx] = o;
        Ab[((size_t)h * 64 + b) * 6016 + c * 200 + l] = f2bfu(o);
    }
    if (c == 0) {   // zero K-pad cols 6000..6015 for this slice's 8 rows
        for (int i = tid; i < 8 * 16; i += 256) {
            const int b = bs * 8 + (i >> 4);
            Ab[((size_t)h * 64 + b) * 6016 + 6000 + (i & 15)] = 0;
        }
    }
}

__global__ __launch_bounds__(256) void bn_fused2(const float* __restrict__ A,
                                                 const float* __restrict__ O,
                                                 unsigned short* __restrict__ Cat,
                                                 const float* __restrict__ g12,
                                                 const float* __restrict__ b12,
                                                 const float* __restrict__ g22,
                                                 const float* __restrict__ b22) {
    const int c = blockIdx.x, h = blockIdx.y, bs = blockIdx.z;
    const int tid = threadIdx.x;
    const size_t cbase = (size_t)h * 64 * 6000 + c * 200;
    float s = 0.f, ss = 0.f;
    for (int i = tid; i < 12800; i += 256) {
        const int b = i / 200, l = i - b * 200;
        const size_t idx = cbase + (size_t)b * 6000 + l;
        const float v = A[idx] + O[idx];
        s += v; ss += v * v;
    }
    for (int off = 32; off > 0; off >>= 1) { s += __shfl_down(s, off); ss += __shfl_down(ss, off); }
    __shared__ float rs[4], rss[4];
    __shared__ float sc_sh, sh_sh;
    const int wave = tid >> 6, lane = tid & 63;
    if (lane == 0) { rs[wave] = s; rss[wave] = ss; }
    __syncthreads();
    if (tid == 0) {
        const float S = rs[0] + rs[1] + rs[2] + rs[3];
        const float SS = rss[0] + rss[1] + rss[2] + rss[3];
        const float mean = S * (1.f / 12800.f);
        const float var = SS * (1.f / 12800.f) - mean * mean;
        const float* gp = h ? g22 : g12;
        const float* bp = h ? b22 : b12;
        const float scale = gp[c] * rsqrtf(var + 1e-5f);
        sc_sh = scale;
        sh_sh = bp[c] - mean * scale;
    }
    __syncthreads();
    const float scale = sc_sh, shift = sh_sh;
    for (int i = tid; i < 1600; i += 256) {
        const int b = bs * 8 + i / 200, l = i % 200;
        const size_t idx = ((size_t)h * 64 + b) * 6000 + c * 200 + l;
        const float o = (A[idx] + O[idx]) * scale + shift;
        Cat[(size_t)b * 12032 + (size_t)h * 6000 + c * 200 + l] = f2bfu(o);
    }
    if (c == 0 && h == 0) {  // zero Cat K-pad cols 12000..12031 for 8 rows
        for (int i = tid; i < 8 * 32; i += 256) {
            const int b = bs * 8 + (i >> 5);
            Cat[(size_t)b * 12032 + 12000 + (i & 31)] = 0;
        }
    }
}

// --------- BK=64 / BN=64 depth-2 counted-vmcnt pipelined split-K GEMM ----
// Each stage reads 256 B per W-row (vs 128 B before) -> 2x DRAM row-buffer
// locality on the strided W sweep. Block: 4 waves x 16 W-rows each, all M
// rows per wave, 2 k-steps per iter (16 MFMA/wave/iter).
// W LDS: [64 rows][64 f32] granule-swizzled j^(row&15); A: [M][64 bf16]
// swizzled j^(m&7). Staged via pre-swizzled-source global_load_lds.
template <int MT>   // M = MT*16
__global__ __launch_bounds__(256) void gemm_pipe(const unsigned short* __restrict__ A,
                                                 const float* __restrict__ W,
                                                 unsigned short* __restrict__ P,
                                                 int N, int K, int KA,
                                                 int iters_total, int iters_per) {
    constexpr int M = MT * 16;
    constexpr int WB = 64 * 64 * 4;       // 16384 B (64 rows x 256 B)
    constexpr int AB = M * 64 * 2;        // M x 128 B
    constexpr int ACH_PW = (AB / 1024) / 4;  // A chunks per wave (MT/2)
    constexpr int BUFSZ = WB + AB;
    constexpr int VMPS = 4 + ACH_PW;      // gload_lds per wave per stage (8 or 6)
    __shared__ __align__(16) char lds[2][BUFSZ];

    const int tid = threadIdx.x;
    const int wave = tid >> 6;
    const int lane = tid & 63;
    const int r = lane & 15;
    const int g = lane >> 4;
    const int n0 = blockIdx.x * 64;
    const int s = blockIdx.y;
    const int it0 = s * iters_per;
    int it1 = it0 + iters_per;
    if (it1 > iters_total) it1 = iters_total;
    const int nst = it1 - it0;

    f32x4 acc[MT] = {};

    // ---- hoisted staging addresses ----
    // W: 16 chunks of 1 KB; chunk c: rows c*4..c*4+3, 16 lanes/row, 16B granules.
    const float* wbase[4];
    const float* wclamp[4];
    int kth[4];
#pragma unroll
    for (int u = 0; u < 4; ++u) {
        const int c = wave + 4 * u;
        const int row = c * 4 + (lane >> 4);
        const int jj = lane & 15;
        const int j = jj ^ (row & 15);
        int rn = n0 + row;
        if (rn > N - 1) rn = N - 1;
        wbase[u] = W + (size_t)rn * K + j * 4;
        wclamp[u] = W + (size_t)rn * K + (K - 4);
        kth[u] = K - 4 - j * 4;
    }
    // A: M/8 chunks; chunk c: rows c*8.., 8 lanes/row, 16B granules (8 bf16).
    const unsigned short* abase[ACH_PW];
#pragma unroll
    for (int u = 0; u < ACH_PW; ++u) {
        const int c = wave + 4 * u;
        const int m = c * 8 + (lane >> 3);
        const int jj = lane & 7;
        const int j = jj ^ (m & 7);
        abase[u] = A + (size_t)m * KA + j * 8;
    }

    auto stage = [&](char* base, int it) {
        const int k0 = it * 64;
#pragma unroll
        for (int u = 0; u < 4; ++u) {
            const float* src = (k0 <= kth[u]) ? (wbase[u] + k0) : wclamp[u];
            gload_lds16(src, base + (wave + 4 * u) * 1024);
        }
        char* ab = base + WB;
#pragma unroll
        for (int u = 0; u < ACH_PW; ++u) {
            gload_lds16(abase[u] + k0, ab + (wave + 4 * u) * 1024);
        }
    };

    auto compute = [&](const char* base) {
        const float* Wb = (const float*)base;
        const unsigned short* Ab = (const unsigned short*)(base + WB);
        const float* Wrow = Wb + (wave * 16 + r) * 64;
        const unsigned short* Arow0 = Ab + (size_t)r * 64;
#pragma unroll
        for (int ks = 0; ks < 2; ++ks) {
            const f32x4 x = ((const f32x4*)Wrow)[(2 * g + 8 * ks) ^ r];
            const f32x4 y = ((const f32x4*)Wrow)[(2 * g + 1 + 8 * ks) ^ r];
            const bf16x8 bfrag = to_bf8(x, y);
            const int ai = (ks * 4 + g) ^ (r & 7);
#pragma unroll
            for (int mt = 0; mt < MT; ++mt) {
                const bf16x8 afrag = __builtin_bit_cast(
                    bf16x8, ((const u16x8*)(Arow0 + (size_t)mt * 1024))[ai]);
                acc[mt] = __builtin_amdgcn_mfma_f32_16x16x32_bf16(afrag, bfrag, acc[mt], 0, 0, 0);
            }
        }
    };

    if (nst > 0) {
        stage(&lds[0][0], it0);
        if (nst > 1) {
            stage(&lds[1][0], it0 + 1);
            waitcnt_vm<VMPS>();
        } else {
            waitcnt_vm<0>();
        }
        __builtin_amdgcn_s_barrier();
        __builtin_amdgcn_sched_barrier(0);

        int cur = 0;
        for (int it = it0; it < it1; ++it) {
            compute(&lds[cur][0]);
            __builtin_amdgcn_sched_barrier(0);
            __builtin_amdgcn_s_barrier();          // buf[cur] free
            if (it + 2 < it1) stage(&lds[cur][0], it + 2);
            if (it + 1 < it1) {
                if (it + 2 < it1) waitcnt_vm<VMPS>();
                else              waitcnt_vm<0>();
                __builtin_amdgcn_s_barrier();
                __builtin_amdgcn_sched_barrier(0);
            }
            cur ^= 1;
        }
    }

    unsigned short* Pp = P + (size_t)s * M * N;
    const int col = n0 + wave * 16 + r;
    if (col < N) {
#pragma unroll
        for (int mt = 0; mt < MT; ++mt) {
#pragma unroll
            for (int rr = 0; rr < 4; ++rr) {
                const int row = mt * 16 + g * 4 + rr;
                Pp[(size_t)row * N + col] = f2bfu(acc[mt][rr]);
            }
        }
    }
}

// Sum KS bf16 partials + bias -> fp32 (flat) or bf16 (stride KOUT, pad-zeroed).
template <bool OUT_BF16>
__global__ __launch_bounds__(256) void reduce_bias(const unsigned short* __restrict__ P,
                                                   const float* __restrict__ bias,
                                                   int KS, int MN, int N, int KOUT,
                                                   float* __restrict__ of,
                                                   unsigned short* __restrict__ ob) {
    const int gid0 = blockIdx.x * 256 + threadIdx.x;
    const int gstr = gridDim.x * 256;
    for (int idx = gid0; idx < MN; idx += gstr) {
        float v = bias[idx % N];
        for (int s = 0; s < KS; ++s) {
            const unsigned u = P[(size_t)s * MN + idx];
            v += __builtin_bit_cast(float, u << 16);
        }
        if constexpr (OUT_BF16) ob[(size_t)(idx / N) * KOUT + (idx % N)] = f2bfu(v);
        else of[idx] = v;
    }
    if constexpr (OUT_BF16) {
        if (KOUT > N) {
            const int M = MN / N, PADW = KOUT - N;
            for (int i = gid0; i < M * PADW; i += gstr)
                ob[(size_t)(i / PADW) * KOUT + N + (i % PADW)] = 0;
        }
    }
}

// ---------------------------------------------------------------- launch ----
extern "C" void kernel_launch(void* const* d_in, const int* in_sizes, int n_in,
                              void* d_out, int out_size, void* d_ws, size_t ws_size,
                              hipStream_t stream) {
    (void)in_sizes; (void)n_in; (void)out_size;
    const float* X = (const float*)d_in[0];
    ConvArgs ca;
    for (int j = 0; j < 6; ++j) {
        ca.w[j] = (const float*)d_in[1 + 2 * j];
        ca.b[j] = (const float*)d_in[2 + 2 * j];
    }
    const float* bn11_g = (const float*)d_in[13];
    const float* bn11_b = (const float*)d_in[14];
    const float* bn12_g = (const float*)d_in[15];
    const float* bn12_b = (const float*)d_in[16];
    const float* bn21_g = (const float*)d_in[17];
    const float* bn21_b = (const float*)d_in[18];
    const float* bn22_g = (const float*)d_in[19];
    const float* bn22_b = (const float*)d_in[20];
    const float* lin1_w = (const float*)d_in[21];
    const float* lin1_b = (const float*)d_in[22];
    const float* lin2_w = (const float*)d_in[23];
    const float* lin2_b = (const float*)d_in[24];
    const float* cw = (const float*)d_in[25];
    const float* cb = (const float*)d_in[26];
    float* out = (float*)d_out;

    // workspace layout (bytes):
    //   A_lin f32 [128][6000]        @ 0           (3,072,000)
    //   A_bf  bf16 [128][6016]       @ 3,072,000   (1,540,096)
    //   U region                     @ 4,612,096   (9,216,000):
    //     phase A: convout [6][64][6000] f32
    //     phase B: T_bf bf16[128][6016] @U, O f32[128][6000] @U+1,540,096,
    //              Cat bf16[64][12032] @U+4,612,096 (1,540,096)
    //   P partials                   @ 13,832,192  (rest, adaptive KS)
    char* w = (char*)d_ws;
    float* A_lin = (float*)w;
    unsigned short* A_bf = (unsigned short*)(w + 3072000);
    char* U = w + 4612096;
    float* convout = (float*)U;
    unsigned short* T_bf = (unsigned short*)U;
    float* O = (float*)(U + 1540096);
    unsigned short* Cat = (unsigned short*)(U + 4612096);
    unsigned short* P = (unsigned short*)(w + 13832192);

    const size_t avail = ws_size > 13832192 ? ws_size - 13832192 : 0;
    int KS12 = (int)(avail / 1536000);  // per-chunk bf16 partials: 128*6000*2 B
    if (KS12 > 5) KS12 = 5;             // 94*5 = 470 blocks @ 2/CU (64KB LDS)
    if (KS12 < 1) KS12 = 1;
    int KS3 = (int)(avail / 768000);    // per-chunk bf16 partials: 64*6000*2 B
    if (KS3 > 8) KS3 = 8;               // 94*8 = 752 blocks @ 3/CU (48KB LDS)
    if (KS3 < 1) KS3 = 1;

    conv_all<<<dim3(64, 6), 256, 0, stream>>>(X, ca, convout);
    attn_k<<<dim3(64, 2), 256, 0, stream>>>(convout, X, A_lin);
    bn_fused1<<<dim3(30, 2, 8), 256, 0, stream>>>(A_lin, A_bf, bn11_g, bn11_b, bn21_g, bn21_b);

    {
        const int it_tot = 94;  // 6016/64 (A zero-padded past 6000)
        const int it_per = (it_tot + KS12 - 1) / KS12;
        gemm_pipe<8><<<dim3(94, KS12), 256, 0, stream>>>(A_bf, lin1_w, P, 6000, 6000, 6016, it_tot, it_per);
        reduce_bias<true><<<dim3(768), 256, 0, stream>>>(P, lin1_b, KS12, 768000, 6000, 6016, nullptr, T_bf);
        gemm_pipe<8><<<dim3(94, KS12), 256, 0, stream>>>(T_bf, lin2_w, P, 6000, 6000, 6016, it_tot, it_per);
        reduce_bias<false><<<dim3(768), 256, 0, stream>>>(P, lin2_b, KS12, 768000, 6000, 6000, O, nullptr);
    }

    bn_fused2<<<dim3(30, 2, 8), 256, 0, stream>>>(A_lin, O, Cat, bn12_g, bn12_b, bn22_g, bn22_b);

    {
        const int it_tot = 188;  // 12032/64 (Cat zero-padded past 12000)
        const int it_per = (it_tot + KS3 - 1) / KS3;
        gemm_pipe<4><<<dim3(94, KS3), 256, 0, stream>>>(Cat, cw, P, 6000, 12000, 12032, it_tot, it_per);
        reduce_bias<false><<<dim3(768), 256, 0, stream>>>(P, cb, KS3, 384000, 6000, 6000, out, nullptr);
    }
}